// Round 16
// baseline (905.745 us; speedup 1.0000x reference)
//
#include <hip/hip_runtime.h>
#include <hip/hip_bf16.h>

// Problem constants
#define N_TOK   576
#define MPAD    640            // padded to 2*320
#define DIM     1024
#define VOCAB   262400
#define BM      320            // tokens per block (5x R9: W costs /5 per FLOP)
#define BN      64
#define BK      64             // k-elements per step (fp8: 64 B rows)
#define RB      2              // MPAD/BM row blocks
#define VBLKS   (VOCAB/BN)     // 4100
#define NWG     (RB*VBLKS)     // 8200
#define IGNORE_INDEX (-100)

typedef float f32x4 __attribute__((ext_vector_type(4)));

#define AS1 __attribute__((address_space(1)))
#define AS3 __attribute__((address_space(3)))

__device__ __forceinline__ int cvt4_fp8(float4 v) {
  int r = __builtin_amdgcn_cvt_pk_fp8_f32(v.x, v.y, 0, false);   // bytes 0,1
  r     = __builtin_amdgcn_cvt_pk_fp8_f32(v.z, v.w, r, true);    // bytes 2,3
  return r;
}

// ---------- kernel 1: fused prep (x->fp8 cvt  +  exact target logits) -----
__global__ void k_prep(const float* __restrict__ x, const float* __restrict__ W,
                       const int* __restrict__ labels,
                       unsigned char* __restrict__ xq, float* __restrict__ tgt) {
  if (blockIdx.x < MPAD * DIM / 2048) {     // ---- cvt part: 320 blocks ----
    int idx = blockIdx.x * 256 + threadIdx.x;
    long e0 = (long)idx * 8;
    int row = (int)(e0 >> 10);
    uint2 o;
    if (row < N_TOK) {
      float4 a = *(const float4*)(x + e0);
      float4 b = *(const float4*)(x + e0 + 4);
      o.x = (unsigned)cvt4_fp8(a);
      o.y = (unsigned)cvt4_fp8(b);
    } else { o.x = o.y = 0u; }
    *(uint2*)(xq + e0) = o;
  } else {                                  // ---- tgt part: 576 blocks ----
    int n = blockIdx.x - MPAD * DIM / 2048;
    int lab = labels[n];
    int t = threadIdx.x;
    float s = 0.0f;
    if (lab >= 0) {
      const float4 a = ((const float4*)(x + (size_t)n * DIM))[t];
      const float4 b = ((const float4*)(W + (size_t)lab * DIM))[t];
      s = a.x*b.x + a.y*b.y + a.z*b.z + a.w*b.w;
    }
    #pragma unroll
    for (int off = 32; off >= 1; off >>= 1) s += __shfl_xor(s, off);
    __shared__ float wsum[4];
    if ((t & 63) == 0) wsum[t >> 6] = s;
    __syncthreads();
    if (t == 0) {
      float d = wsum[0] + wsum[1] + wsum[2] + wsum[3];
      tgt[n] = (lab >= 0) ? 30.0f * tanhf(d * (1.0f / 30.0f)) : 0.0f;
    }
  }
}

// ---------- kernel 2: fp8 GEMM, R9 internals at 320x64 geometry -----------
// R9's proven pieces verbatim: paired-row fp8 LDS layout (two 64B rows per
// 128B line; 16B chunk j of row r at chunk ((s*4+j)^(p&7)), p=r>>1,s=r&1),
// A via global_load_lds (linear dest, inverse-swizzled source), B reg-staged
// fp32 -> cvt_pk_fp8 -> swizzled b64 writes, 2x __syncthreads per K-step,
// XCD swizzle, same epilogue. ONLY the tile shape changes: 320x64 block,
// wave-tile 160x32 (acc[10][2]). Per-FLOP costs vs R9: W fp32 L2 reads /5.1,
// cvt VALU /5, B LDS writes /5, B frag reads /5; A terms unchanged. (R14
// showed W-side cost scaling dominates: halving BN doubled W/FLOP -> 2x
// slower; this is the same lever pulled the other way.)
__global__ __launch_bounds__(256, 2) void k_gemm(
    const float* __restrict__ W,            // [VOCAB][DIM] fp32
    const unsigned char* __restrict__ Xq,   // [MPAD][DIM] fp8
    float* __restrict__ S)                  // [MPAD] running sum of exp(z-30)
{
  __shared__ unsigned char Asl[BM * BK];    // 20 KB (160 lines x 128 B)
  __shared__ unsigned char Bsl[BN * BK];    //  4 KB ( 32 lines x 128 B)

  // ---- bijective XCD swizzle (m204), rb-fastest logical order ----
  const int q  = NWG / 8, rm = NWG % 8;     // 1025, 0
  const int orig = blockIdx.x;
  const int xcd  = orig & 7;
  const int part = orig >> 3;
  const int bid  = (xcd < rm ? xcd * (q + 1) : rm * (q + 1) + (xcd - rm) * q) + part;

  const int rb  = bid % RB;
  const int vb  = bid / RB;
  const int m0  = rb * BM;
  const long n0 = (long)vb * BN;

  const int t   = threadIdx.x;
  const int l   = t & 63;
  const int w   = t >> 6;
  const int wm  = w >> 1, wn = w & 1;       // 2x2 waves, wave tile 160M x 32N
  const int l15 = l & 15, lh = l >> 4;

  // ---- A staging: gload_lds linear dest, inverse-swizzled source ----
  // 1280 chunks = 256 threads x 5; lin -> p=lin>>3 (line), c=(lin&7)^(p&7)
  // -> source row 2p+(c>>2), 16B chunk (c&3).
  const unsigned char* asrc[5];
  #pragma unroll
  for (int i = 0; i < 5; ++i) {
    int lin = t + i * 256;                  // 0..1279
    int p   = lin >> 3;
    int c   = (lin & 7) ^ (p & 7);
    asrc[i] = Xq + (size_t)(m0 + 2 * p + (c >> 2)) * DIM + (c & 3) * 16;
  }
  // ---- B staging: 512 granules = 256 threads x 2; 8 floats -> 8 fp8 ----
  const float* bsrc[2];
  int boff[2];
  #pragma unroll
  for (int i = 0; i < 2; ++i) {
    int lin = t + i * 256;                  // 0..511
    int r   = lin >> 3;                     // row 0..63
    int g   = lin & 7;
    bsrc[i] = W + (n0 + r) * DIM + g * 8;
    int p = r >> 1, s = r & 1;
    int jj = g >> 1, hb = g & 1;
    boff[i] = p * 128 + ((((s << 2) | jj) ^ (p & 7)) << 4) + (hb << 3);
  }
  // ---- frag read offsets (paired-row swizzle; rows are 16-aligned so
  //      line&7 == l15>>1 for both A and B bases) ----
  const int pr = l15 >> 1, sr = l15 & 1;
  int fo[2];
  #pragma unroll
  for (int kk = 0; kk < 2; ++kk)
    fo[kk] = pr * 128 + (((((sr << 2) | (kk * 2 + (lh >> 1))) ^ pr)) << 4)
           + ((lh & 1) << 3);
  const int abase = wm * 10240;             // wm*160 rows x 64B
  const int bbase = wn * 2048;              // wn*32 rows x 64B

  f32x4 acc[10][2];
  const f32x4 zero4 = {0.0f, 0.0f, 0.0f, 0.0f};
  #pragma unroll
  for (int i = 0; i < 10; ++i) {
    acc[i][0] = zero4; acc[i][1] = zero4;
  }

  for (int k0 = 0; k0 < DIM; k0 += BK) {
    // -- B global loads issued BEFORE the barrier (hide under prev MFMA) --
    float4 fb[2][2];
    #pragma unroll
    for (int i = 0; i < 2; ++i) {
      fb[i][0] = *(const float4*)(bsrc[i] + k0);
      fb[i][1] = *(const float4*)(bsrc[i] + k0 + 4);
    }
    __syncthreads();                        // prev-iter frag reads done
    // -- A: 5 x 16B direct global->LDS --
    #pragma unroll
    for (int i = 0; i < 5; ++i)
      __builtin_amdgcn_global_load_lds((const AS1 void*)(asrc[i] + k0),
          (AS3 void*)(Asl + (t + i * 256) * 16), 16, 0, 0);
    // -- B: cvt fp32->fp8, swizzled 8B writes --
    #pragma unroll
    for (int i = 0; i < 2; ++i) {
      int lo = cvt4_fp8(fb[i][0]);
      int hi = cvt4_fp8(fb[i][1]);
      *(int2*)(Bsl + boff[i]) = make_int2(lo, hi);
    }
    __syncthreads();                        // tiles ready

    // -- B frags first (4 longs), then per-mi A frags + MFMA (caps live
    //    registers: 2 A-longs at a time instead of 20) --
    long bf[2][2];
    #pragma unroll
    for (int ni = 0; ni < 2; ++ni) {
      bf[ni][0] = *(const long*)(Bsl + bbase + ni * 1024 + fo[0]);
      bf[ni][1] = *(const long*)(Bsl + bbase + ni * 1024 + fo[1]);
    }
    __builtin_amdgcn_s_setprio(1);
    #pragma unroll
    for (int mi = 0; mi < 10; ++mi) {
      long af0 = *(const long*)(Asl + abase + mi * 1024 + fo[0]);
      long af1 = *(const long*)(Asl + abase + mi * 1024 + fo[1]);
      #pragma unroll
      for (int ni = 0; ni < 2; ++ni) {
        acc[mi][ni] = __builtin_amdgcn_mfma_f32_16x16x32_fp8_fp8(
            af0, bf[ni][0], acc[mi][ni], 0, 0, 0);
        acc[mi][ni] = __builtin_amdgcn_mfma_f32_16x16x32_fp8_fp8(
            af1, bf[ni][1], acc[mi][ni], 0, 0, 0);
      }
    }
    __builtin_amdgcn_s_setprio(0);
  }

  // ---- epilogue: p = exp(z-30) = exp(-60/(exp(g/15)+1)); row sums; atomics
  // C frag layout (HW-validated R7-R15): col = l15, row = lh*4 + j
  #pragma unroll
  for (int mi = 0; mi < 10; ++mi) {
    #pragma unroll
    for (int j = 0; j < 4; ++j) {
      float s = 0.0f;
      #pragma unroll
      for (int ni = 0; ni < 2; ++ni) {
        float g   = acc[mi][ni][j];
        float tp1 = __expf(g * (1.0f / 15.0f)) + 1.0f;
        s += __expf(-60.0f * __builtin_amdgcn_rcpf(tp1));
      }
      s += __shfl_xor(s, 1);
      s += __shfl_xor(s, 2);
      s += __shfl_xor(s, 4);
      s += __shfl_xor(s, 8);
      if (l15 == 0) {
        int row = m0 + wm * 160 + mi * 16 + lh * 4 + j;
        atomicAdd(&S[row], s);              // padded rows land in S[576..640)
      }
    }
  }
}

// ---------- kernel 3: final reduce -> loss ----------
__global__ void k_final(const float* __restrict__ S, const float* __restrict__ tgt,
                        const int* __restrict__ labels, float* __restrict__ out) {
  int t = threadIdx.x;
  float sum = 0.0f, cnt = 0.0f;
  for (int n = t; n < N_TOK; n += 256) {
    if (labels[n] != IGNORE_INDEX) {
      sum += 30.0f + __logf(S[n]) - tgt[n];  // lse = 30 + log(sum exp(z-30))
      cnt += 1.0f;
    }
  }
  #pragma unroll
  for (int off = 32; off >= 1; off >>= 1) {
    sum += __shfl_xor(sum, off);
    cnt += __shfl_xor(cnt, off);
  }
  __shared__ float as_[4], ac_[4];
  if ((t & 63) == 0) { as_[t >> 6] = sum; ac_[t >> 6] = cnt; }
  __syncthreads();
  if (t == 0) out[0] = (as_[0]+as_[1]+as_[2]+as_[3]) / (ac_[0]+ac_[1]+ac_[2]+ac_[3]);
}

extern "C" void kernel_launch(void* const* d_in, const int* in_sizes, int n_in,
                              void* d_out, int out_size, void* d_ws, size_t ws_size,
                              hipStream_t stream) {
  const float* x      = (const float*)d_in[0];
  const float* W      = (const float*)d_in[1];
  const int*   labels = (const int*)d_in[2];
  float* out = (float*)d_out;

  // ws layout: xq [640*1024 fp8] | S [640 f32] | tgt [576 f32]  (~0.66 MB)
  char* ws = (char*)d_ws;
  unsigned char* xq = (unsigned char*)ws;
  float* S   = (float*)(ws + (size_t)MPAD * DIM);
  float* tgt = S + MPAD;

  hipMemsetAsync(S, 0, MPAD * sizeof(float), stream);   // zero accumulators
  k_prep<<<MPAD * DIM / 2048 + N_TOK, 256, 0, stream>>>(x, W, labels, xq, tgt);
  k_gemm<<<NWG, 256, 0, stream>>>(W, xq, S);
  k_final<<<1, 256, 0, stream>>>(S, tgt, labels, out);
}

// Round 17
// 483.433 us; speedup vs baseline: 1.8736x; 1.8736x over previous
//
#include <hip/hip_runtime.h>
#include <hip/hip_bf16.h>

// Problem constants
#define N_TOK   576
#define MPAD    640            // padded to 5*128
#define DIM     1024
#define VOCAB   262400
#define BM      128
#define BN      128
#define BK      64             // k-elements per step (fp8: 64 B rows)
#define RB      5              // MPAD/BM row blocks
#define VBLKS   (VOCAB/BN)     // 2050
#define NWG     (RB*VBLKS)     // 10250
#define IGNORE_INDEX (-100)

typedef float f32x4 __attribute__((ext_vector_type(4)));

#define AS1 __attribute__((address_space(1)))
#define AS3 __attribute__((address_space(3)))

__device__ __forceinline__ int cvt4_fp8(float4 v) {
  int r = __builtin_amdgcn_cvt_pk_fp8_f32(v.x, v.y, 0, false);   // bytes 0,1
  r     = __builtin_amdgcn_cvt_pk_fp8_f32(v.z, v.w, r, true);    // bytes 2,3
  return r;
}

// ---------- kernel 1: fused prep (x->fp8 cvt  +  exact target logits) -----
__global__ void k_prep(const float* __restrict__ x, const float* __restrict__ W,
                       const int* __restrict__ labels,
                       unsigned char* __restrict__ xq, float* __restrict__ tgt) {
  if (blockIdx.x < MPAD * DIM / 2048) {     // ---- cvt part: 320 blocks ----
    int idx = blockIdx.x * 256 + threadIdx.x;
    long e0 = (long)idx * 8;
    int row = (int)(e0 >> 10);
    uint2 o;
    if (row < N_TOK) {
      float4 a = *(const float4*)(x + e0);
      float4 b = *(const float4*)(x + e0 + 4);
      o.x = (unsigned)cvt4_fp8(a);
      o.y = (unsigned)cvt4_fp8(b);
    } else { o.x = o.y = 0u; }
    *(uint2*)(xq + e0) = o;
  } else {                                  // ---- tgt part: 576 blocks ----
    int n = blockIdx.x - MPAD * DIM / 2048;
    int lab = labels[n];
    int t = threadIdx.x;
    float s = 0.0f;
    if (lab >= 0) {
      const float4 a = ((const float4*)(x + (size_t)n * DIM))[t];
      const float4 b = ((const float4*)(W + (size_t)lab * DIM))[t];
      s = a.x*b.x + a.y*b.y + a.z*b.z + a.w*b.w;
    }
    #pragma unroll
    for (int off = 32; off >= 1; off >>= 1) s += __shfl_xor(s, off);
    __shared__ float wsum[4];
    if ((t & 63) == 0) wsum[t >> 6] = s;
    __syncthreads();
    if (t == 0) {
      float d = wsum[0] + wsum[1] + wsum[2] + wsum[3];
      tgt[n] = (lab >= 0) ? 30.0f * tanhf(d * (1.0f / 30.0f)) : 0.0f;
    }
  }
}

// ---------- kernel 2: single-pass fp8 GEMM (R9, session best) -------------
// 2-barrier skeleton; LDS tiles fp8 with PAIRED-ROW layout: two 64B rows
// share a 128B LDS line. Row r -> pair p=r>>1, parity s=r&1; 16B chunk j of
// row r stored at combined slot ((s*4+j) ^ (p&7)) within the line (residual
// 2-lane/bank aliasing is free per m136 -- R15 proved eliminating it gains
// nothing). A staged via global_load_lds (linear dest, inverse-swizzled
// source); B reg-staged fp32 -> v_cvt_pk_fp8 -> swizzled ds_write_b64.
// MFMA 16x16x32 fp8: A/B use identical slot->k maps so any HW slot
// permutation cancels. Target logit exact fp32 (k_prep) -> absmax ~0.
// Plateau ledger: scheduling (R3/4/6/11), raw barriers (R10/11), MX (R12/13),
// occupancy up (R14), conflict-free+reg-A (R15), tile reshape (R14/16) all
// regress or null -- 128x128x64 @ 4 waves, 64x64 wave tile, 128 regs/thread
// is the register-file-constrained optimum of this structure.
__global__ __launch_bounds__(256, 4) void k_gemm(
    const float* __restrict__ W,            // [VOCAB][DIM] fp32
    const unsigned char* __restrict__ Xq,   // [MPAD][DIM] fp8
    float* __restrict__ S)                  // [MPAD] running sum of exp(z-30)
{
  __shared__ unsigned char Asl[BM * BK];    // 8 KB (64 pair-lines x 128 B)
  __shared__ unsigned char Bsl[BN * BK];    // 8 KB

  // ---- bijective XCD swizzle (m204), rb-fastest logical order ----
  const int q  = NWG / 8, rm = NWG % 8;     // 1281, 2
  const int orig = blockIdx.x;
  const int xcd  = orig & 7;
  const int part = orig >> 3;
  const int bid  = (xcd < rm ? xcd * (q + 1) : rm * (q + 1) + (xcd - rm) * q) + part;

  const int rb  = bid % RB;
  const int vb  = bid / RB;
  const int m0  = rb * BM;
  const long n0 = (long)vb * BN;

  const int t   = threadIdx.x;
  const int l   = t & 63;
  const int w   = t >> 6;
  const int wm  = w >> 1, wn = w & 1;       // 2x2 waves, 64x64 per wave
  const int l15 = l & 15, lh = l >> 4;

  // ---- A staging: global_load_lds, linear dest, inverse-swizzled source ----
  const unsigned char* asrc[2];
  #pragma unroll
  for (int i = 0; i < 2; ++i) {
    int lin = t + i * 256;                  // 0..511
    int p   = lin >> 3;
    int c   = (lin & 7) ^ (p & 7);
    asrc[i] = Xq + (size_t)(m0 + 2 * p + (c >> 2)) * DIM + (c & 3) * 16;
  }
  // ---- B staging: 8 floats/thread/i -> 8 fp8 at swizzled 8B slot ----
  const float* bsrc[4];
  int boff[4];
  #pragma unroll
  for (int i = 0; i < 4; ++i) {
    int lin = t + i * 256;                  // 0..1023
    int r   = lin >> 3;                     // row 0..127
    int g   = lin & 7;
    bsrc[i] = W + (n0 + r) * DIM + g * 8;
    int p = r >> 1, s = r & 1;
    int jj = g >> 1, hb = g & 1;            // 16B chunk, 8B half
    boff[i] = p * 128 + ((((s << 2) | jj) ^ (p & 7)) << 4) + (hb << 3);
  }
  // ---- frag read offsets (paired-row swizzle) ----
  const int pr = l15 >> 1, sr = l15 & 1;
  int fo[2];
  #pragma unroll
  for (int kk = 0; kk < 2; ++kk)
    fo[kk] = pr * 128 + (((((sr << 2) | (kk * 2 + (lh >> 1))) ^ pr)) << 4)
           + ((lh & 1) << 3);
  const int abase = wm * 4096;              // wm*64 rows = wm*32 pair-lines
  const int bbase = wn * 4096;

  f32x4 acc[4][4];
  const f32x4 zero4 = {0.0f, 0.0f, 0.0f, 0.0f};
  #pragma unroll
  for (int i = 0; i < 4; ++i)
    #pragma unroll
    for (int j = 0; j < 4; ++j) acc[i][j] = zero4;

  for (int k0 = 0; k0 < DIM; k0 += BK) {
    // -- B global loads issued BEFORE the barrier (hide under prev MFMA) --
    float4 fb[4][2];
    #pragma unroll
    for (int i = 0; i < 4; ++i) {
      fb[i][0] = *(const float4*)(bsrc[i] + k0);
      fb[i][1] = *(const float4*)(bsrc[i] + k0 + 4);
    }
    __syncthreads();                        // prev-iter frag reads done
    // -- A: 2 x 16B direct global->LDS --
    #pragma unroll
    for (int i = 0; i < 2; ++i)
      __builtin_amdgcn_global_load_lds((const AS1 void*)(asrc[i] + k0),
          (AS3 void*)(Asl + (t + i * 256) * 16), 16, 0, 0);
    // -- B: cvt fp32->fp8, swizzled 8B writes --
    #pragma unroll
    for (int i = 0; i < 4; ++i) {
      int lo = cvt4_fp8(fb[i][0]);
      int hi = cvt4_fp8(fb[i][1]);
      *(int2*)(Bsl + boff[i]) = make_int2(lo, hi);
    }
    __syncthreads();                        // drains vmcnt+lgkmcnt: tiles ready

    // -- fragments (ds_read_b64) + MFMA --
    long af[4][2], bf[4][2];
    #pragma unroll
    for (int mi = 0; mi < 4; ++mi) {
      af[mi][0] = *(const long*)(Asl + abase + mi * 1024 + fo[0]);
      af[mi][1] = *(const long*)(Asl + abase + mi * 1024 + fo[1]);
    }
    #pragma unroll
    for (int ni = 0; ni < 4; ++ni) {
      bf[ni][0] = *(const long*)(Bsl + bbase + ni * 1024 + fo[0]);
      bf[ni][1] = *(const long*)(Bsl + bbase + ni * 1024 + fo[1]);
    }
    __builtin_amdgcn_s_setprio(1);
    #pragma unroll
    for (int kk = 0; kk < 2; ++kk)
      #pragma unroll
      for (int mi = 0; mi < 4; ++mi)
        #pragma unroll
        for (int ni = 0; ni < 4; ++ni)
          acc[mi][ni] = __builtin_amdgcn_mfma_f32_16x16x32_fp8_fp8(
              af[mi][kk], bf[ni][kk], acc[mi][ni], 0, 0, 0);
    __builtin_amdgcn_s_setprio(0);
  }

  // ---- epilogue: p = exp(z-30) = exp(-60/(exp(g/15)+1)); row sums; atomics
  // C frag layout (HW-validated R7-R16): col = l15, row = lh*4 + j
  #pragma unroll
  for (int mi = 0; mi < 4; ++mi) {
    #pragma unroll
    for (int j = 0; j < 4; ++j) {
      float s = 0.0f;
      #pragma unroll
      for (int ni = 0; ni < 4; ++ni) {
        float g   = acc[mi][ni][j];
        float tp1 = __expf(g * (1.0f / 15.0f)) + 1.0f;
        s += __expf(-60.0f * __builtin_amdgcn_rcpf(tp1));
      }
      s += __shfl_xor(s, 1);
      s += __shfl_xor(s, 2);
      s += __shfl_xor(s, 4);
      s += __shfl_xor(s, 8);
      if (l15 == 0) {
        int row = m0 + wm * 64 + mi * 16 + lh * 4 + j;
        atomicAdd(&S[row], s);              // padded rows land in S[576..640)
      }
    }
  }
}

// ---------- kernel 3: final reduce -> loss ----------
__global__ void k_final(const float* __restrict__ S, const float* __restrict__ tgt,
                        const int* __restrict__ labels, float* __restrict__ out) {
  int t = threadIdx.x;
  float sum = 0.0f, cnt = 0.0f;
  for (int n = t; n < N_TOK; n += 256) {
    if (labels[n] != IGNORE_INDEX) {
      sum += 30.0f + __logf(S[n]) - tgt[n];  // lse = 30 + log(sum exp(z-30))
      cnt += 1.0f;
    }
  }
  #pragma unroll
  for (int off = 32; off >= 1; off >>= 1) {
    sum += __shfl_xor(sum, off);
    cnt += __shfl_xor(cnt, off);
  }
  __shared__ float as_[4], ac_[4];
  if ((t & 63) == 0) { as_[t >> 6] = sum; ac_[t >> 6] = cnt; }
  __syncthreads();
  if (t == 0) out[0] = (as_[0]+as_[1]+as_[2]+as_[3]) / (ac_[0]+ac_[1]+ac_[2]+ac_[3]);
}

extern "C" void kernel_launch(void* const* d_in, const int* in_sizes, int n_in,
                              void* d_out, int out_size, void* d_ws, size_t ws_size,
                              hipStream_t stream) {
  const float* x      = (const float*)d_in[0];
  const float* W      = (const float*)d_in[1];
  const int*   labels = (const int*)d_in[2];
  float* out = (float*)d_out;

  // ws layout: xq [640*1024 fp8] | S [640 f32] | tgt [576 f32]  (~0.66 MB)
  char* ws = (char*)d_ws;
  unsigned char* xq = (unsigned char*)ws;
  float* S   = (float*)(ws + (size_t)MPAD * DIM);
  float* tgt = S + MPAD;

  hipMemsetAsync(S, 0, MPAD * sizeof(float), stream);   // zero accumulators
  k_prep<<<MPAD * DIM / 2048 + N_TOK, 256, 0, stream>>>(x, W, labels, xq, tgt);
  k_gemm<<<NWG, 256, 0, stream>>>(W, xq, S);
  k_final<<<1, 256, 0, stream>>>(S, tgt, labels, out);
}